// Round 2
// baseline (72.213 us; speedup 1.0000x reference)
//
#include <hip/hip_runtime.h>

static constexpr int B = 8, Himg = 512, Wimg = 512, TH = 512, TW = 512;

__device__ __forceinline__ unsigned f2ord(float f) {
    unsigned u = __float_as_uint(f);
    return (u & 0x80000000u) ? ~u : (u | 0x80000000u);
}
__device__ __forceinline__ float ord2f(unsigned u) {
    return (u & 0x80000000u) ? __uint_as_float(u & 0x7fffffffu) : __uint_as_float(~u);
}

__global__ void init_ws_kernel(unsigned* ws) {
    int t = threadIdx.x;
    if (t < B) ws[t] = 0xFFFFFFFFu;            // min slots (ordered encoding)
    else if (t < 2 * B) ws[t] = 0u;            // max slots
}

__global__ __launch_bounds__(256) void minmax_kernel(const float* __restrict__ cm,
                                                     unsigned* __restrict__ ws) {
    const int BPB = 32;                         // blocks per batch
    int b = blockIdx.x / BPB;
    int blk = blockIdx.x % BPB;
    const int N = Himg * Wimg;                  // 262144
    const float4* p = (const float4*)(cm + (size_t)b * N);
    int n4 = N / 4;
    float mn = 3.4e38f, mx = -3.4e38f;
    for (int i = blk * 256 + threadIdx.x; i < n4; i += BPB * 256) {
        float4 v = p[i];
        mn = fminf(mn, fminf(fminf(v.x, v.y), fminf(v.z, v.w)));
        mx = fmaxf(mx, fmaxf(fmaxf(v.x, v.y), fmaxf(v.z, v.w)));
    }
    #pragma unroll
    for (int off = 32; off; off >>= 1) {
        mn = fminf(mn, __shfl_xor(mn, off));
        mx = fmaxf(mx, __shfl_xor(mx, off));
    }
    __shared__ float smn[4], smx[4];
    int wave = threadIdx.x >> 6, lane = threadIdx.x & 63;
    if (lane == 0) { smn[wave] = mn; smx[wave] = mx; }
    __syncthreads();
    if (threadIdx.x == 0) {
        mn = fminf(fminf(smn[0], smn[1]), fminf(smn[2], smn[3]));
        mx = fmaxf(fmaxf(smx[0], smx[1]), fmaxf(smx[2], smx[3]));
        atomicMin(&ws[b], f2ord(mn));
        atomicMax(&ws[B + b], f2ord(mx));
    }
}

// Fused: f64 normalize + 5x5 conv + density + threshold decisions + sampling.
// f64 keeps us ~1e-15 from the numpy-f64 reference so the discrete
// num_samples decisions (0.4 / 0.7 thresholds) never flip.
__global__ __launch_bounds__(256) void fused_kernel(const float* __restrict__ cm,
                                                    const float* __restrict__ kern,
                                                    const float* __restrict__ rnd,
                                                    const unsigned* __restrict__ ws,
                                                    float* __restrict__ coords,
                                                    float* __restrict__ weights,
                                                    float* __restrict__ dens) {
    __shared__ double tile[36][37];
    __shared__ double kd[25];
    int tid = threadIdx.x;
    int b = blockIdx.z;
    int bx = blockIdx.x * 32, by = blockIdx.y * 32;
    if (tid < 25) kd[tid] = (double)kern[tid];
    float mnf = ord2f(ws[b]);
    float mxf = ord2f(ws[B + b]);
    bool ok = mxf > mnf;
    double mn = (double)mnf;
    double d = ok ? ((double)mxf - mn) : 1.0;
    const float* img = cm + (size_t)b * Himg * Wimg;
    for (int idx = tid; idx < 36 * 36; idx += 256) {
        int r = idx / 36, c = idx % 36;
        int gy = by + r - 2, gx = bx + c - 2;
        double v = 0.0;
        if (gy >= 0 && gy < Himg && gx >= 0 && gx < Wimg) {
            double x = (double)img[gy * Wimg + gx];
            v = ok ? (x - mn) / d : 0.0;
        }
        tile[r][c] = v;
    }
    __syncthreads();

    const float cy = (2.0f / TH) * 0.8f;
    const float cx = (2.0f / TW) * 0.8f;
    for (int p = tid; p < 32 * 32; p += 256) {
        int oy = p >> 5, ox = p & 31;
        double s = 0.0;
        #pragma unroll
        for (int dy = 0; dy < 5; ++dy)
            #pragma unroll
            for (int dx = 0; dx < 5; ++dx)
                s += tile[oy + dy][ox + dx] * kd[dy * 5 + dx];
        double D = 0.1 + 0.9 * sqrt(s);         // f64 density

        int gy = by + oy, gx = bx + ox;
        size_t pix = (size_t)b * Himg * Wimg + (size_t)gy * Wimg + gx;
        dens[pix] = (float)D;

        int num = D > 0.7 ? 4 : (D > 0.4 ? 2 : 1);
        bool useoff = num > 1;

        float yb = -1.0f + gy * (2.0f / (TH - 1));
        float xb = -1.0f + gx * (2.0f / (TW - 1));
        float4 r01 = *(const float4*)(rnd + pix * 8);
        float4 r23 = *(const float4*)(rnd + pix * 8 + 4);
        float4 c01, c23;
        c01.x = yb + (useoff ? (r01.x - 0.5f) * cy : 0.0f);
        c01.y = xb + (useoff ? (r01.y - 0.5f) * cx : 0.0f);
        c01.z = yb + (useoff ? (r01.z - 0.5f) * cy : 0.0f);
        c01.w = xb + (useoff ? (r01.w - 0.5f) * cx : 0.0f);
        c23.x = yb + (useoff ? (r23.x - 0.5f) * cy : 0.0f);
        c23.y = xb + (useoff ? (r23.y - 0.5f) * cx : 0.0f);
        c23.z = yb + (useoff ? (r23.z - 0.5f) * cy : 0.0f);
        c23.w = xb + (useoff ? (r23.w - 0.5f) * cx : 0.0f);
        *(float4*)(coords + pix * 8) = c01;
        *(float4*)(coords + pix * 8 + 4) = c23;

        float inv = (float)(D / (double)num);
        float4 w;
        w.x = inv;
        w.y = (num > 1) ? inv : 0.0f;
        w.z = (num > 3) ? inv : 0.0f;
        w.w = (num > 3) ? inv : 0.0f;
        *(float4*)(weights + pix * 4) = w;
    }
}

extern "C" void kernel_launch(void* const* d_in, const int* in_sizes, int n_in,
                              void* d_out, int out_size, void* d_ws, size_t ws_size,
                              hipStream_t stream) {
    const float* cm   = (const float*)d_in[0];
    const float* rnd  = (const float*)d_in[1];
    const float* kern = (const float*)d_in[2];
    float* out     = (float*)d_out;
    float* coords  = out;                                   // 8*512*512*4*2
    float* weights = out + (size_t)B * TH * TW * 8;         // 8*512*512*4
    float* dens    = weights + (size_t)B * TH * TW * 4;     // 8*512*512
    unsigned* ws   = (unsigned*)d_ws;

    init_ws_kernel<<<1, 64, 0, stream>>>(ws);
    minmax_kernel<<<B * 32, 256, 0, stream>>>(cm, ws);
    dim3 gridC(Wimg / 32, Himg / 32, B);
    fused_kernel<<<gridC, 256, 0, stream>>>(cm, kern, rnd, ws, coords, weights, dens);
}

// Round 3
// 52.404 us; speedup vs baseline: 1.3780x; 1.3780x over previous
//
#include <hip/hip_runtime.h>

static constexpr int B = 8, Himg = 512, Wimg = 512, TH = 512, TW = 512;
static constexpr int NPIX = B * Himg * Wimg;          // 2,097,152
static constexpr int BPB = 32;                        // minmax blocks per batch

// ---------------- kernel 1: per-block min/max partials (no atomics) --------
__global__ __launch_bounds__(256) void minmax_kernel(const float* __restrict__ cm,
                                                     float* __restrict__ wsmin,
                                                     float* __restrict__ wsmax) {
    int b   = blockIdx.x / BPB;
    int blk = blockIdx.x % BPB;
    const float4* p = (const float4*)(cm + (size_t)b * Himg * Wimg);
    float mn = 3.4e38f, mx = -3.4e38f;
    // 65536 float4 per batch, 2048 per block, 8 per thread
    int base = blk * 2048;
    #pragma unroll
    for (int k = 0; k < 8; ++k) {
        float4 v = p[base + k * 256 + threadIdx.x];
        mn = fminf(mn, fminf(fminf(v.x, v.y), fminf(v.z, v.w)));
        mx = fmaxf(mx, fmaxf(fmaxf(v.x, v.y), fmaxf(v.z, v.w)));
    }
    #pragma unroll
    for (int off = 32; off; off >>= 1) {
        mn = fminf(mn, __shfl_xor(mn, off));
        mx = fmaxf(mx, __shfl_xor(mx, off));
    }
    __shared__ float smn[4], smx[4];
    int wave = threadIdx.x >> 6, lane = threadIdx.x & 63;
    if (lane == 0) { smn[wave] = mn; smx[wave] = mx; }
    __syncthreads();
    if (threadIdx.x == 0) {
        mn = fminf(fminf(smn[0], smn[1]), fminf(smn[2], smn[3]));
        mx = fmaxf(fmaxf(smx[0], smx[1]), fmaxf(smx[2], smx[3]));
        wsmin[b * BPB + blk] = mn;
        wsmax[b * BPB + blk] = mx;
    }
}

// ---------------- kernel 2: f64 normalize + 5x5 conv -> density ------------
// f64 keeps the 0.4/0.7 threshold decisions aligned with the numpy-f64
// reference (~1e-15). The decision (num_samples) is encoded into the 2 low
// mantissa bits of the f32 density (error ~1e-7 << 2e-2 threshold) so the
// sampler never re-derives it from f32.
__global__ __launch_bounds__(256) void density_kernel(const float* __restrict__ cm,
                                                      const float* __restrict__ kern,
                                                      const float* __restrict__ wsmin,
                                                      const float* __restrict__ wsmax,
                                                      float* __restrict__ dens) {
    __shared__ double tile[36][37];
    __shared__ double kd[25];
    int tid = threadIdx.x;
    int b = blockIdx.z;
    int bx = blockIdx.x * 32, by = blockIdx.y * 32;
    if (tid < 25) kd[tid] = (double)kern[tid];

    float mnf = 3.4e38f, mxf = -3.4e38f;
    #pragma unroll
    for (int k = 0; k < BPB; ++k) {             // L2-broadcast reads, cheap
        mnf = fminf(mnf, wsmin[b * BPB + k]);
        mxf = fmaxf(mxf, wsmax[b * BPB + k]);
    }
    bool ok = mxf > mnf;
    double mn = (double)mnf;
    double d = ok ? ((double)mxf - mn) : 1.0;

    const float* img = cm + (size_t)b * Himg * Wimg;
    for (int idx = tid; idx < 36 * 36; idx += 256) {
        int r = idx / 36, c = idx % 36;
        int gy = by + r - 2, gx = bx + c - 2;
        double v = 0.0;
        if (gy >= 0 && gy < Himg && gx >= 0 && gx < Wimg) {
            double x = (double)img[gy * Wimg + gx];
            v = ok ? (x - mn) / d : 0.0;
        }
        tile[r][c] = v;
    }
    __syncthreads();

    for (int p = tid; p < 32 * 32; p += 256) {
        int oy = p >> 5, ox = p & 31;
        double s = 0.0;
        #pragma unroll
        for (int dy = 0; dy < 5; ++dy)
            #pragma unroll
            for (int dx = 0; dx < 5; ++dx)
                s += tile[oy + dy][ox + dx] * kd[dy * 5 + dx];
        double D = 0.1 + 0.9 * sqrt(s);
        int code = D > 0.7 ? 2 : (D > 0.4 ? 1 : 0);   // num = 1<<code

        unsigned u = __float_as_uint((float)D);
        u = (u & ~3u) | (unsigned)code;
        dens[(size_t)b * Himg * Wimg + (size_t)(by + oy) * Wimg + (bx + ox)] =
            __uint_as_float(u);
    }
}

// ---------------- kernel 3: pure-streaming sampler -------------------------
__global__ __launch_bounds__(256) void sample_kernel(const float* __restrict__ rnd,
                                                     const float* __restrict__ dens,
                                                     float* __restrict__ coords,
                                                     float* __restrict__ weights) {
    int g = blockIdx.x * 256 + threadIdx.x;     // pixel id, grid == NPIX/256
    float local = dens[g];
    unsigned u = __float_as_uint(local);
    int code = u & 3;
    int num = 1 << code;                        // exact decision from kernel 2
    bool useoff = num > 1;

    int rem = g & (Himg * Wimg - 1);
    int i = rem >> 9;                           // row
    int j = rem & 511;                          // col
    float yb = -1.0f + i * (2.0f / (TH - 1));
    float xb = -1.0f + j * (2.0f / (TW - 1));
    const float cy = (2.0f / TH) * 0.8f;
    const float cx = (2.0f / TW) * 0.8f;

    float4 r01 = *(const float4*)(rnd + (size_t)g * 8);
    float4 r23 = *(const float4*)(rnd + (size_t)g * 8 + 4);
    float4 c01, c23;
    c01.x = yb + (useoff ? (r01.x - 0.5f) * cy : 0.0f);
    c01.y = xb + (useoff ? (r01.y - 0.5f) * cx : 0.0f);
    c01.z = yb + (useoff ? (r01.z - 0.5f) * cy : 0.0f);
    c01.w = xb + (useoff ? (r01.w - 0.5f) * cx : 0.0f);
    c23.x = yb + (useoff ? (r23.x - 0.5f) * cy : 0.0f);
    c23.y = xb + (useoff ? (r23.y - 0.5f) * cx : 0.0f);
    c23.z = yb + (useoff ? (r23.z - 0.5f) * cy : 0.0f);
    c23.w = xb + (useoff ? (r23.w - 0.5f) * cx : 0.0f);
    *(float4*)(coords + (size_t)g * 8) = c01;
    *(float4*)(coords + (size_t)g * 8 + 4) = c23;

    float inv = local / (float)num;             // num is a power of two: exact scale
    float4 w;
    w.x = inv;
    w.y = (num > 1) ? inv : 0.0f;
    w.z = (num > 3) ? inv : 0.0f;
    w.w = (num > 3) ? inv : 0.0f;
    *(float4*)(weights + (size_t)g * 4) = w;
}

extern "C" void kernel_launch(void* const* d_in, const int* in_sizes, int n_in,
                              void* d_out, int out_size, void* d_ws, size_t ws_size,
                              hipStream_t stream) {
    const float* cm   = (const float*)d_in[0];
    const float* rnd  = (const float*)d_in[1];
    const float* kern = (const float*)d_in[2];
    float* out     = (float*)d_out;
    float* coords  = out;                                   // 8*512*512*4*2
    float* weights = out + (size_t)B * TH * TW * 8;         // 8*512*512*4
    float* dens    = weights + (size_t)B * TH * TW * 4;     // 8*512*512
    float* wsmin   = (float*)d_ws;                          // 256 floats
    float* wsmax   = wsmin + B * BPB;                       // 256 floats

    minmax_kernel<<<B * BPB, 256, 0, stream>>>(cm, wsmin, wsmax);
    dim3 gridC(Wimg / 32, Himg / 32, B);
    density_kernel<<<gridC, 256, 0, stream>>>(cm, kern, wsmin, wsmax, dens);
    sample_kernel<<<NPIX / 256, 256, 0, stream>>>(rnd, dens, coords, weights);
}